// Round 3
// baseline (381.263 us; speedup 1.0000x reference)
//
#include <hip/hip_runtime.h>
#include <hip/hip_bf16.h>

#define D_MODEL 1024
#define NH 8
#define HD 128
#define BATCH 4
#define TSEQ 2048
#define MROWS (BATCH * TSEQ)  // 8192

typedef __attribute__((ext_vector_type(8))) __bf16 bf16x8;
typedef __attribute__((ext_vector_type(4))) __bf16 bf16x4;
typedef __attribute__((ext_vector_type(4))) float f32x4;
typedef __attribute__((ext_vector_type(8))) unsigned short u16x8;

#define SC2 0.1275174441680632f  // (1/sqrt(128)) * log2(e)

__device__ __forceinline__ void gload16(const void* g, void* lds) {
  __builtin_amdgcn_global_load_lds(
      (const __attribute__((address_space(1))) unsigned int*)g,
      (__attribute__((address_space(3))) unsigned int*)lds, 16, 0, 0);
}

// ---------------- fp32 -> bf16 conversion ----------------
__global__ __launch_bounds__(256) void cvt_f32_to_bf16(const float* __restrict__ in,
                                                       __bf16* __restrict__ out, int n4) {
  int i = blockIdx.x * 256 + threadIdx.x;
  if (i < n4) {
    float4 v = reinterpret_cast<const float4*>(in)[i];
    bf16x4 o;
    o[0] = (__bf16)v.x; o[1] = (__bf16)v.y; o[2] = (__bf16)v.z; o[3] = (__bf16)v.w;
    reinterpret_cast<bf16x4*>(out)[i] = o;
  }
}

// 4 weight matrices (1024x1024 each) in one launch; outputs contiguous.
__global__ __launch_bounds__(256) void cvt4_weights(const float* __restrict__ w0,
                                                    const float* __restrict__ w1,
                                                    const float* __restrict__ w2,
                                                    const float* __restrict__ w3,
                                                    __bf16* __restrict__ out) {
  const int per = D_MODEL * D_MODEL / 4;  // float4s per matrix
  int i = blockIdx.x * 256 + threadIdx.x;
  int m = i / per, j = i - m * per;
  const float* src = (m == 0) ? w0 : (m == 1) ? w1 : (m == 2) ? w2 : w3;
  float4 v = reinterpret_cast<const float4*>(src)[j];
  bf16x4 o;
  o[0] = (__bf16)v.x; o[1] = (__bf16)v.y; o[2] = (__bf16)v.z; o[3] = (__bf16)v.w;
  reinterpret_cast<bf16x4*>(out)[i] = o;
}

// ---------------- generic 128x128 GEMM:  Y = A @ B^T (+bias), 2-phase dbuf ----
template <bool BF16OUT, bool CAUSAL, bool AFP32>
__global__ __launch_bounds__(256) void gemm128(const void* __restrict__ Aip,
                                               const __bf16* __restrict__ Bp,
                                               const float* __restrict__ bias,
                                               void* __restrict__ Yp, int K, int ldy,
                                               size_t sA, size_t sB, size_t sY) {
  __shared__ __bf16 As[2][128 * 32];
  __shared__ __bf16 Bs[2][128 * 32];
  const int tid = threadIdx.x;
  const int w = tid >> 6, l = tid & 63;
  const int lr = l & 15, lg = l >> 4;
  const int m0 = blockIdx.y * 128, n0 = blockIdx.x * 128;
  const int z = blockIdx.z;
  const __bf16* Ab = AFP32 ? nullptr : (const __bf16*)Aip + z * sA;
  const float* Af = AFP32 ? (const float*)Aip + z * sA : nullptr;
  const __bf16* Bb = Bp + z * sB;
  const int wm = w >> 1, wn = w & 1;
  f32x4 acc[4][4] = {};
  const int Klim = CAUSAL ? (m0 + 128 < K ? m0 + 128 : K) : K;
  const int nt = Klim >> 5;

  auto stage = [&](int t, int buf) {
    const int k0 = t << 5;
    if constexpr (!AFP32) {
#pragma unroll
      for (int i = 0; i < 2; ++i) {
        int s = w * 128 + i * 64 + l;
        int row = s >> 2, scp = s & 3;
        int sc = scp ^ ((row >> 1) & 3);
        gload16(Ab + (size_t)(m0 + row) * K + k0 + sc * 8, (char*)As[buf] + s * 16);
      }
    } else {
#pragma unroll
      for (int i = 0; i < 2; ++i) {
        int s = w * 128 + i * 64 + l;
        int row = s >> 2, sc = s & 3;
        const float* src = Af + (size_t)(m0 + row) * K + k0 + sc * 8;
        float4 lo = *reinterpret_cast<const float4*>(src);
        float4 hi = *reinterpret_cast<const float4*>(src + 4);
        bf16x8 v;
        v[0] = (__bf16)lo.x; v[1] = (__bf16)lo.y; v[2] = (__bf16)lo.z; v[3] = (__bf16)lo.w;
        v[4] = (__bf16)hi.x; v[5] = (__bf16)hi.y; v[6] = (__bf16)hi.z; v[7] = (__bf16)hi.w;
        int p = row * 4 + (sc ^ ((row >> 1) & 3));
        *reinterpret_cast<bf16x8*>((char*)As[buf] + p * 16) = v;
      }
    }
#pragma unroll
    for (int i = 0; i < 2; ++i) {
      int s = w * 128 + i * 64 + l;
      int row = s >> 2, scp = s & 3;
      int sc = scp ^ ((row >> 1) & 3);
      gload16(Bb + (size_t)(n0 + row) * K + k0 + sc * 8, (char*)Bs[buf] + s * 16);
    }
  };

  stage(0, 0);
  __syncthreads();
  int cur = 0;
  for (int t = 0; t < nt; ++t) {
    if (t + 1 < nt) stage(t + 1, cur ^ 1);
    bf16x8 af[4], bf[4];
#pragma unroll
    for (int f = 0; f < 4; ++f) {
      int ar = wm * 64 + f * 16 + lr;
      af[f] = *reinterpret_cast<const bf16x8*>((const char*)As[cur] + ar * 64 +
                                               ((lg ^ ((ar >> 1) & 3)) * 16));
      int br = wn * 64 + f * 16 + lr;
      bf[f] = *reinterpret_cast<const bf16x8*>((const char*)Bs[cur] + br * 64 +
                                               ((lg ^ ((br >> 1) & 3)) * 16));
    }
#pragma unroll
    for (int mf = 0; mf < 4; ++mf)
#pragma unroll
      for (int nf = 0; nf < 4; ++nf)
        acc[mf][nf] = __builtin_amdgcn_mfma_f32_16x16x32_bf16(af[mf], bf[nf], acc[mf][nf], 0, 0, 0);
    __syncthreads();
    cur ^= 1;
  }

#pragma unroll
  for (int mf = 0; mf < 4; ++mf) {
#pragma unroll
    for (int nf = 0; nf < 4; ++nf) {
#pragma unroll
      for (int r = 0; r < 4; ++r) {
        int grow = m0 + wm * 64 + mf * 16 + lg * 4 + r;
        int gcol = n0 + wn * 64 + nf * 16 + lr;
        float v = acc[mf][nf][r];
        if (bias) v += bias[gcol];
        if constexpr (BF16OUT)
          ((__bf16*)Yp + z * sY)[(size_t)grow * ldy + gcol] = (__bf16)v;
        else
          ((float*)Yp + z * sY)[(size_t)grow * ldy + gcol] = v;
      }
    }
  }
}

// ---------------- V[b][t][d] -> Vt[b][d][t] ----------------
__global__ __launch_bounds__(256) void transpose_v(const __bf16* __restrict__ V,
                                                   __bf16* __restrict__ Vt) {
  __shared__ unsigned short tile[64 * 72];
  const int b = blockIdx.z;
  const int t0 = blockIdx.x * 64, d0 = blockIdx.y * 64;
  const int tid = threadIdx.x;
#pragma unroll
  for (int i = 0; i < 2; ++i) {
    int s = i * 256 + tid;
    int r = s >> 3, c8 = s & 7;
    u16x8 v = *reinterpret_cast<const u16x8*>(V + ((size_t)b * TSEQ + t0 + r) * D_MODEL + d0 + c8 * 8);
    *reinterpret_cast<u16x8*>(&tile[r * 72 + c8 * 8]) = v;
  }
  __syncthreads();
#pragma unroll
  for (int i = 0; i < 2; ++i) {
    int s = i * 256 + tid;
    int dr = s >> 3, t8 = s & 7;
    u16x8 o;
#pragma unroll
    for (int j = 0; j < 8; ++j) o[j] = tile[(t8 * 8 + j) * 72 + dr];
    *reinterpret_cast<u16x8*>(Vt + ((size_t)b * D_MODEL + d0 + dr) * TSEQ + t0 + t8 * 8) = o;
  }
}

// ---- [64][128] bf16 tile staging; full 16-seg XOR swizzle: phys = log ^ (row&15)
#define STAGE_T(srcbase, dst)                                                      \
  {                                                                                \
    _Pragma("unroll") for (int i = 0; i < 4; ++i) {                                \
      int s = i * 256 + tid;                                                       \
      int row = s >> 4, sp = s & 15;                                               \
      int sl = sp ^ (row & 15);                                                    \
      gload16((srcbase) + (size_t)row * D_MODEL + sl * 8, (char*)(dst) + s * 16);  \
    }                                                                              \
  }

__device__ __forceinline__ bf16x8 ldfrag(const __bf16* t, int row, int c, int lg) {
  return *reinterpret_cast<const bf16x8*>((const char*)t + row * 256 +
                                          (((c * 4 + lg) ^ (row & 15)) * 16));
}

// ---------------- Pass A: Linv[b][h][q] = 1/(H * sum_k exp(s)) ----------------
// Block (qt64, b*h). Q-frags persistent in regs; K 2-phase double-buffered.
// 4 waves as 2x2 quadrants of the 64x64 score tile.
__global__ __launch_bounds__(256) void attn_stats(const __bf16* __restrict__ Q,
                                                  const __bf16* __restrict__ Kp,
                                                  float* __restrict__ Linv) {
  __shared__ __bf16 Qs[64 * 128];
  __shared__ __bf16 Ks[2][64 * 128];
  __shared__ float Lred[2][64];
  const int tid = threadIdx.x;
  const int w = tid >> 6, l = tid & 63;
  const int lr = l & 15, lg = l >> 4;
  const int wq = w >> 1, wk = w & 1;
  const int qt = blockIdx.x, q0 = qt * 64;
  const int b = blockIdx.y >> 3, h = blockIdx.y & 7;

  const __bf16* qsrc = Q + ((size_t)(b * TSEQ + q0)) * D_MODEL + h * HD;
  const __bf16* kbase = Kp + ((size_t)b * TSEQ) * D_MODEL + h * HD;
  STAGE_T(qsrc, Qs);
  STAGE_T(kbase, Ks[0]);
  __syncthreads();

  bf16x8 af[2][4];
#pragma unroll
  for (int mf = 0; mf < 2; ++mf)
#pragma unroll
    for (int c = 0; c < 4; ++c) af[mf][c] = ldfrag(Qs, wq * 32 + mf * 16 + lr, c, lg);

  float lsum[2][4] = {};
  int cur = 0;
  for (int kt = 0; kt <= qt; ++kt) {
    if (kt < qt) STAGE_T(kbase + (size_t)(kt + 1) * 64 * D_MODEL, Ks[cur ^ 1]);
    bf16x8 bfr[2][4];
#pragma unroll
    for (int nf = 0; nf < 2; ++nf)
#pragma unroll
      for (int c = 0; c < 4; ++c) bfr[nf][c] = ldfrag(Ks[cur], wk * 32 + nf * 16 + lr, c, lg);
    f32x4 acc[2][2] = {};
#pragma unroll
    for (int c = 0; c < 4; ++c)
#pragma unroll
      for (int mf = 0; mf < 2; ++mf)
#pragma unroll
        for (int nf = 0; nf < 2; ++nf)
          acc[mf][nf] = __builtin_amdgcn_mfma_f32_16x16x32_bf16(af[mf][c], bfr[nf][c], acc[mf][nf], 0, 0, 0);
    if (kt == qt) {
#pragma unroll
      for (int mf = 0; mf < 2; ++mf)
#pragma unroll
        for (int nf = 0; nf < 2; ++nf)
#pragma unroll
          for (int r = 0; r < 4; ++r) {
            int q = q0 + wq * 32 + mf * 16 + lg * 4 + r;
            int k = kt * 64 + wk * 32 + nf * 16 + lr;
            if (k <= q) lsum[mf][r] += exp2f(acc[mf][nf][r] * SC2);
          }
    } else {
#pragma unroll
      for (int mf = 0; mf < 2; ++mf)
#pragma unroll
        for (int nf = 0; nf < 2; ++nf)
#pragma unroll
          for (int r = 0; r < 4; ++r) lsum[mf][r] += exp2f(acc[mf][nf][r] * SC2);
    }
    __syncthreads();
    cur ^= 1;
  }
#pragma unroll
  for (int m = 1; m < 16; m <<= 1)
#pragma unroll
    for (int mf = 0; mf < 2; ++mf)
#pragma unroll
      for (int r = 0; r < 4; ++r) lsum[mf][r] += __shfl_xor(lsum[mf][r], m, 64);
  if (lr == 0) {
#pragma unroll
    for (int mf = 0; mf < 2; ++mf)
#pragma unroll
      for (int r = 0; r < 4; ++r) Lred[wk][wq * 32 + mf * 16 + lg * 4 + r] = lsum[mf][r];
  }
  __syncthreads();
  if (tid < 64) {
    float s = Lred[0][tid] + Lred[1][tid];
    Linv[((size_t)(b * NH + h)) * TSEQ + q0 + tid] = 1.0f / (8.0f * s);
  }
}

// ---------------- Pass B: alpha[b][q][k] = sum_h exp(s_h)*Linv ----------------
// Block (kt, qt, b); 2-phase double-buffered per-head Q/K staging.
__global__ __launch_bounds__(256) void attn_alpha(const __bf16* __restrict__ Q,
                                                  const __bf16* __restrict__ Kp,
                                                  const float* __restrict__ Linv,
                                                  float* __restrict__ alpha) {
  const int kt = blockIdx.x, qt = blockIdx.y, b = blockIdx.z;
  const int q0 = qt * 64, k0 = kt * 64;
  const int tid = threadIdx.x;
  if (kt > qt) {
    float4 zz = {0.f, 0.f, 0.f, 0.f};
#pragma unroll
    for (int i = 0; i < 4; ++i) {
      int s = i * 256 + tid;
      int row = s >> 4, c4 = s & 15;
      *reinterpret_cast<float4*>(alpha + ((size_t)(b * TSEQ) + q0 + row) * TSEQ + k0 + c4 * 4) = zz;
    }
    return;
  }
  __shared__ __bf16 Qs[2][64 * 128];
  __shared__ __bf16 Ks[2][64 * 128];
  const int w = tid >> 6, l = tid & 63;
  const int lr = l & 15, lg = l >> 4;
  const int wq = w >> 1, wk = w & 1;
  const __bf16* qb0 = Q + ((size_t)(b * TSEQ + q0)) * D_MODEL;
  const __bf16* kb0 = Kp + ((size_t)(b * TSEQ + k0)) * D_MODEL;
  float outv[2][2][4] = {};

  STAGE_T(qb0, Qs[0]);
  STAGE_T(kb0, Ks[0]);
  __syncthreads();
  int cur = 0;
  for (int h = 0; h < NH; ++h) {
    if (h + 1 < NH) {
      STAGE_T(qb0 + (h + 1) * HD, Qs[cur ^ 1]);
      STAGE_T(kb0 + (h + 1) * HD, Ks[cur ^ 1]);
    }
    bf16x8 af[2][4], bfr[2][4];
#pragma unroll
    for (int mf = 0; mf < 2; ++mf)
#pragma unroll
      for (int c = 0; c < 4; ++c) af[mf][c] = ldfrag(Qs[cur], wq * 32 + mf * 16 + lr, c, lg);
#pragma unroll
    for (int nf = 0; nf < 2; ++nf)
#pragma unroll
      for (int c = 0; c < 4; ++c) bfr[nf][c] = ldfrag(Ks[cur], wk * 32 + nf * 16 + lr, c, lg);
    f32x4 acc[2][2] = {};
#pragma unroll
    for (int c = 0; c < 4; ++c)
#pragma unroll
      for (int mf = 0; mf < 2; ++mf)
#pragma unroll
        for (int nf = 0; nf < 2; ++nf)
          acc[mf][nf] = __builtin_amdgcn_mfma_f32_16x16x32_bf16(af[mf][c], bfr[nf][c], acc[mf][nf], 0, 0, 0);
    float4 li[2];
#pragma unroll
    for (int mf = 0; mf < 2; ++mf)
      li[mf] = *reinterpret_cast<const float4*>(
          &Linv[((size_t)(b * NH + h)) * TSEQ + q0 + wq * 32 + mf * 16 + lg * 4]);
    if (kt == qt) {
#pragma unroll
      for (int mf = 0; mf < 2; ++mf)
#pragma unroll
        for (int nf = 0; nf < 2; ++nf)
#pragma unroll
          for (int r = 0; r < 4; ++r) {
            int q = q0 + wq * 32 + mf * 16 + lg * 4 + r;
            int k = k0 + wk * 32 + nf * 16 + lr;
            if (k <= q)
              outv[mf][nf][r] += exp2f(acc[mf][nf][r] * SC2) * (&li[mf].x)[r];
          }
    } else {
#pragma unroll
      for (int mf = 0; mf < 2; ++mf)
#pragma unroll
        for (int nf = 0; nf < 2; ++nf)
#pragma unroll
          for (int r = 0; r < 4; ++r)
            outv[mf][nf][r] += exp2f(acc[mf][nf][r] * SC2) * (&li[mf].x)[r];
    }
    __syncthreads();
    cur ^= 1;
  }
#pragma unroll
  for (int mf = 0; mf < 2; ++mf)
#pragma unroll
    for (int nf = 0; nf < 2; ++nf)
#pragma unroll
      for (int r = 0; r < 4; ++r)
        alpha[((size_t)(b * TSEQ) + q0 + wq * 32 + mf * 16 + lg * 4 + r) * TSEQ +
              k0 + wk * 32 + nf * 16 + lr] = outv[mf][nf][r];
}

extern "C" void kernel_launch(void* const* d_in, const int* in_sizes, int n_in,
                              void* d_out, int out_size, void* d_ws, size_t ws_size,
                              hipStream_t stream) {
  const float* x  = (const float*)d_in[0];
  const float* Wq = (const float*)d_in[2];
  const float* bq = (const float*)d_in[3];
  const float* Wk = (const float*)d_in[4];
  const float* bk = (const float*)d_in[5];
  const float* Wv = (const float*)d_in[6];
  const float* bv = (const float*)d_in[7];
  const float* Wo = (const float*)d_in[8];
  const float* bo = (const float*)d_in[9];

  float* out_f = (float*)d_out;                    // [4,2048,1024]
  float* alpha = out_f + (size_t)MROWS * D_MODEL;  // [4,2048,2048]

  char* p = (char*)d_ws;
  __bf16* xb  = (__bf16*)p; p += (size_t)MROWS * D_MODEL * 2;   // reused as midb
  __bf16* wqb = (__bf16*)p; p += (size_t)D_MODEL * D_MODEL * 2;
  __bf16* wkb = (__bf16*)p; p += (size_t)D_MODEL * D_MODEL * 2;
  __bf16* wvb = (__bf16*)p; p += (size_t)D_MODEL * D_MODEL * 2;
  __bf16* wob = (__bf16*)p; p += (size_t)D_MODEL * D_MODEL * 2;
  __bf16* qb  = (__bf16*)p; p += (size_t)MROWS * D_MODEL * 2;
  __bf16* kb  = (__bf16*)p; p += (size_t)MROWS * D_MODEL * 2;
  __bf16* vb  = (__bf16*)p; p += (size_t)MROWS * D_MODEL * 2;
  __bf16* vtb = (__bf16*)p; p += (size_t)BATCH * D_MODEL * TSEQ * 2;
  float* linv = (float*)p;  p += (size_t)BATCH * NH * TSEQ * 4;
  __bf16* midb = xb;

  // 1) bf16 conversions
  {
    int n4 = MROWS * D_MODEL / 4;
    cvt_f32_to_bf16<<<n4 / 256, 256, 0, stream>>>(x, xb, n4);
    int w4 = 4 * D_MODEL * D_MODEL / 4;
    cvt4_weights<<<w4 / 256, 256, 0, stream>>>(Wq, Wk, Wv, Wo, wqb);
  }

  // 2) projections
  dim3 pgrid(D_MODEL / 128, MROWS / 128, 1);
  gemm128<true, false, false><<<pgrid, 256, 0, stream>>>(xb, wqb, bq, qb, D_MODEL, D_MODEL, 0, 0, 0);
  gemm128<true, false, false><<<pgrid, 256, 0, stream>>>(xb, wkb, bk, kb, D_MODEL, D_MODEL, 0, 0, 0);
  gemm128<true, false, false><<<pgrid, 256, 0, stream>>>(xb, wvb, bv, vb, D_MODEL, D_MODEL, 0, 0, 0);

  // 3) V transpose
  transpose_v<<<dim3(TSEQ / 64, D_MODEL / 64, BATCH), 256, 0, stream>>>(vb, vtb);

  // 4) softmax denominators
  attn_stats<<<dim3(TSEQ / 64, BATCH * NH), 256, 0, stream>>>(qb, kb, linv);

  // 5) head-averaged attention -> alpha
  attn_alpha<<<dim3(TSEQ / 64, TSEQ / 64, BATCH), 256, 0, stream>>>(qb, kb, linv, alpha);

  // 6) Mid = alpha @ V
  gemm128<true, true, true><<<dim3(D_MODEL / 128, TSEQ / 128, BATCH), 256, 0, stream>>>(
      alpha, vtb, nullptr, midb, TSEQ, D_MODEL,
      (size_t)TSEQ * TSEQ, (size_t)D_MODEL * TSEQ, (size_t)TSEQ * D_MODEL);

  // 7) out = Mid @ Wo^T + bo
  gemm128<false, false, false><<<pgrid, 256, 0, stream>>>(midb, wob, bo, out_f, D_MODEL, D_MODEL, 0, 0, 0);
}